// Round 12
// baseline (273.862 us; speedup 1.0000x reference)
//
#include <hip/hip_runtime.h>

#define NNODES 100000
#define NEDGES 6400000
#define NPAIRS (NEDGES / 2)
#define NQUAD  (NEDGES / 8)   // 4 pairs (8 edges) per thread
#define DFEAT 128
#define ODIM 128

// Fixed-point: FXSCALE=2^9, 15-bit biased fields (bias 2^14), |I| clamped <32.
// LDS accumulator packing [cnt:12][re:26][im:26]: each add contributes bias
// 2^14 exactly; field sums < 300*2^15 << 2^26; cnt < 4096. Integer adds
// associative -> bit-deterministic regardless of processing order.
#define FXSCALE 512.0f
#define INV_FXSCALE (1.0f / 512.0f)
#define IBIAS 16384
#define FMASK 0x3FFFFFFULL

#define RANGE 20352          // nodes per LDS range: 20352*8B = 159 KB LDS
#define NRANGE 5             // 5*20352 = 101760 >= 100000
#define NC_MAX 51            // 51*5 = 255 blocks (1 per CU, LDS-bound)

typedef unsigned long long ull;
typedef float  __attribute__((ext_vector_type(4))) fx4;   // native vec for NT stores
typedef unsigned long long __attribute__((ext_vector_type(2))) ux2;

__device__ __forceinline__ int qfx(float x) {
    return min(max(__float2int_rn(x * FXSCALE), -IBIAS), IBIAS - 1);
}
__device__ __forceinline__ ull mkrec(int r, int s, int qre, int qim) {
    return ((ull)(unsigned)r << 47) | ((ull)(unsigned)s << 30)
         | ((ull)(unsigned)(qre + IBIAS) << 15) | (unsigned)(qim + IBIAS);
}
__device__ __forceinline__ void nt_store4(float4* dst, float4 v) {
    fx4 t = {v.x, v.y, v.z, v.w};
    __builtin_nontemporal_store(t, reinterpret_cast<fx4*>(dst));
}

// -------- Kernel 1: compact V2 table --------
__global__ __launch_bounds__(256) void prep_kernel(const float* __restrict__ Vn,
                                                   float2* __restrict__ v2) {
    int i = blockIdx.x * 256 + threadIdx.x;
    if (i < NNODES)
        v2[i] = make_float2(Vn[i * DFEAT + 0], Vn[i * DFEAT + 1]);
}

// -------- Kernel 2: streaming edge compute + u64 record emit --------
__global__ __launch_bounds__(256) void stream_kernel(const int4* __restrict__ s4,
                                                     const int4* __restrict__ r4,
                                                     const float4* __restrict__ ef2,
                                                     const float2* __restrict__ v2,
                                                     float4* __restrict__ I2,
                                                     float4* __restrict__ V2e,
                                                     ull* __restrict__ rec) {
    int t = blockIdx.x * 256 + threadIdx.x;
    if (t >= NQUAD) return;
    int4 sA = s4[2 * t], sB = s4[2 * t + 1];
    int4 rA = r4[2 * t], rB = r4[2 * t + 1];
    int p = 4 * t;
    float4 e0 = ef2[p + 0], e1 = ef2[p + 1], e2 = ef2[p + 2], e3 = ef2[p + 3];

    float2 vr0 = v2[rA.x], vr1 = v2[rA.y], vr2 = v2[rA.z], vr3 = v2[rA.w];
    float2 vr4 = v2[rB.x], vr5 = v2[rB.y], vr6 = v2[rB.z], vr7 = v2[rB.w];
    float2 vs0 = v2[sA.x], vs1 = v2[sA.y], vs2 = v2[sA.z], vs3 = v2[sA.w];
    float2 vs4 = v2[sB.x], vs5 = v2[sB.y], vs6 = v2[sB.z], vs7 = v2[sB.w];

#define EDGE(vex, vey, ire, iim, vr, vs, G, B)       \
    float vex = vr.x - vs.x, vey = vr.y - vs.y;      \
    float ire = G * vex - B * vey;                   \
    float iim = G * vey + B * vex;

    EDGE(x0, y0, a0, b0, vr0, vs0, e0.x, e0.y)
    EDGE(x1, y1, a1, b1, vr1, vs1, e0.z, e0.w)
    EDGE(x2, y2, a2, b2, vr2, vs2, e1.x, e1.y)
    EDGE(x3, y3, a3, b3, vr3, vs3, e1.z, e1.w)
    EDGE(x4, y4, a4, b4, vr4, vs4, e2.x, e2.y)
    EDGE(x5, y5, a5, b5, vr5, vs5, e2.z, e2.w)
    EDGE(x6, y6, a6, b6, vr6, vs6, e3.x, e3.y)
    EDGE(x7, y7, a7, b7, vr7, vs7, e3.z, e3.w)
#undef EDGE

    float4 V0 = make_float4(x0, y0, x1, y1), V1 = make_float4(x2, y2, x3, y3);
    float4 V2_ = make_float4(x4, y4, x5, y5), V3 = make_float4(x6, y6, x7, y7);
    float4 I0 = make_float4(a0, b0, a1, b1), I1 = make_float4(a2, b2, a3, b3);
    float4 I4 = make_float4(a4, b4, a5, b5), I5 = make_float4(a6, b6, a7, b7);

    if (rec) {
        // write-only streams: nontemporal so the rec array owns the L3
        nt_store4(&V2e[p + 0], V0);
        nt_store4(&V2e[p + 1], V1);
        nt_store4(&V2e[p + 2], V2_);
        nt_store4(&V2e[p + 3], V3);
        nt_store4(&I2[p + 0], I0);
        nt_store4(&I2[p + 1], I1);
        nt_store4(&I2[p + 2], I4);
        nt_store4(&I2[p + 3], I5);

        ux2* rp = reinterpret_cast<ux2*>(rec + 8 * (size_t)t);
        ux2 r0 = {mkrec(rA.x, sA.x, qfx(a0), qfx(b0)),
                  mkrec(rA.y, sA.y, qfx(a1), qfx(b1))};
        ux2 r1 = {mkrec(rA.z, sA.z, qfx(a2), qfx(b2)),
                  mkrec(rA.w, sA.w, qfx(a3), qfx(b3))};
        ux2 r2_ = {mkrec(rB.x, sB.x, qfx(a4), qfx(b4)),
                   mkrec(rB.y, sB.y, qfx(a5), qfx(b5))};
        ux2 r3 = {mkrec(rB.z, sB.z, qfx(a6), qfx(b6)),
                  mkrec(rB.w, sB.w, qfx(a7), qfx(b7))};
        rp[0] = r0; rp[1] = r1; rp[2] = r2_; rp[3] = r3;
    } else {
        V2e[p + 0] = V0;  V2e[p + 1] = V1;  V2e[p + 2] = V2_; V2e[p + 3] = V3;
        I2[p + 0]  = I0;  I2[p + 1]  = I1;  I2[p + 2]  = I4;  I2[p + 3]  = I5;
    }
}

// -------- Kernel 3a: record-based range reduce (5 passes over 51MB L3) -----
__global__ __launch_bounds__(1024) void reduce_rec_kernel(const ull* __restrict__ rec,
                                                          ull* __restrict__ partial,
                                                          int NC, int epc) {
    __shared__ ull acc[RANGE];       // 159 KB
    const int ri   = blockIdx.y;
    const int base = ri * RANGE;
    for (int i = threadIdx.x; i < RANGE; i += 1024) acc[i] = 0ULL;
    __syncthreads();

    const int e0 = blockIdx.x * epc;
    const int e1 = min(e0 + epc, NEDGES);
    for (int e = e0 + threadIdx.x; e < e1; e += 1024) {
        ull rc = rec[e];
        int r = (int)(rc >> 47);
        int s = (int)((rc >> 30) & 0x1FFFF);
        unsigned re_b = (unsigned)(rc >> 15) & 0x7FFF;
        unsigned im_b = (unsigned)rc & 0x7FFF;
        int d = r - base;            // receiver: +I
        if ((unsigned)d < RANGE)
            atomicAdd(&acc[d], (1ULL << 52) | ((ull)re_b << 26) | im_b);
        d = s - base;                // sender: -I  (32768-x keeps bias 2^14)
        if ((unsigned)d < RANGE)
            atomicAdd(&acc[d], (1ULL << 52) | ((ull)(32768u - re_b) << 26)
                               | (ull)(32768u - im_b));
    }
    __syncthreads();

    ull* dst = partial + ((size_t)(ri * NC + blockIdx.x)) * RANGE;
    for (int i = threadIdx.x; i < RANGE; i += 1024) dst[i] = acc[i];
}

// -------- Kernel 3b: fallback reduce (reads s,r,I; used if ws too small) ---
__global__ __launch_bounds__(1024) void reduce_kernel(const int2* __restrict__ s2,
                                                      const int2* __restrict__ r2,
                                                      const float4* __restrict__ I2,
                                                      ull* __restrict__ partial,
                                                      int NC, int ppc) {
    __shared__ ull acc[RANGE];
    const int ri   = blockIdx.y;
    const int base = ri * RANGE;
    for (int i = threadIdx.x; i < RANGE; i += 1024) acc[i] = 0ULL;
    __syncthreads();

    const int p0 = blockIdx.x * ppc;
    const int p1 = min(p0 + ppc, NPAIRS);
    for (int p = p0 + threadIdx.x; p < p1; p += 1024) {
        int2 ss = s2[p];
        int2 rr = r2[p];
        float4 II = I2[p];
        int re0 = qfx(II.x), im0 = qfx(II.y);
        int re1 = qfx(II.z), im1 = qfx(II.w);
        int d;
        d = rr.x - base;
        if ((unsigned)d < RANGE)
            atomicAdd(&acc[d], (1ULL << 52)
                | ((ull)(unsigned)(IBIAS + re0) << 26) | (unsigned)(IBIAS + im0));
        d = ss.x - base;
        if ((unsigned)d < RANGE)
            atomicAdd(&acc[d], (1ULL << 52)
                | ((ull)(unsigned)(IBIAS - re0) << 26) | (unsigned)(IBIAS - im0));
        d = rr.y - base;
        if ((unsigned)d < RANGE)
            atomicAdd(&acc[d], (1ULL << 52)
                | ((ull)(unsigned)(IBIAS + re1) << 26) | (unsigned)(IBIAS + im1));
        d = ss.y - base;
        if ((unsigned)d < RANGE)
            atomicAdd(&acc[d], (1ULL << 52)
                | ((ull)(unsigned)(IBIAS - re1) << 26) | (unsigned)(IBIAS - im1));
    }
    __syncthreads();

    ull* dst = partial + ((size_t)(ri * NC + blockIdx.x)) * RANGE;
    for (int i = threadIdx.x; i < RANGE; i += 1024) dst[i] = acc[i];
}

// -------- Kernel 4: sum partials over chunks, decode --------
__global__ __launch_bounds__(256) void decode_kernel(const ull* __restrict__ partial,
                                                     float2* __restrict__ net,
                                                     int NC) {
    int n = blockIdx.x * 256 + threadIdx.x;
    if (n >= NNODES) return;
    int ri = n / RANGE;
    int idx = n - ri * RANGE;
    ull p = 0ULL;
    for (int c = 0; c < NC; ++c)
        p += partial[((size_t)(ri * NC + c)) * RANGE + idx];
    int cnt   = (int)(p >> 52);
    int re_fx = (int)((p >> 26) & FMASK) - cnt * IBIAS;
    int im_fx = (int)(p & FMASK) - cnt * IBIAS;
    net[n] = make_float2((float)re_fx * INV_FXSCALE, (float)im_fx * INV_FXSCALE);
}

// -------- Kernel 5: node MLP  out = relu([V_node, net] @ W + b) --------
#define BN 64
#define TPAD 132

__global__ __launch_bounds__(256) void mlp_kernel(const float* __restrict__ Vn,
                                                  const float2* __restrict__ net,
                                                  const float* __restrict__ W,
                                                  const float* __restrict__ b,
                                                  float* __restrict__ out) {
    __shared__ float tile[BN][TPAD];
    const int n0 = blockIdx.x * BN;
    const int tid = threadIdx.x;

    for (int i = tid; i < BN * (DFEAT / 4); i += 256) {
        int node = i >> 5;
        int k4 = (i & 31) * 4;
        int gn = n0 + node;
        float4 v;
        if (gn < NNODES) v = *reinterpret_cast<const float4*>(&Vn[gn * DFEAT + k4]);
        else             v = make_float4(0.f, 0.f, 0.f, 0.f);
        *reinterpret_cast<float4*>(&tile[node][k4]) = v;
    }
    if (tid < BN) {
        int gn = n0 + tid;
        float2 nc = (gn < NNODES) ? net[gn] : make_float2(0.f, 0.f);
        tile[tid][128] = nc.x;
        tile[tid][129] = nc.y;
    }
    __syncthreads();

    const int lane = tid & 63;
    const int col0 = __builtin_amdgcn_readfirstlane((tid >> 6) * 32);

    float acc[32];
#pragma unroll
    for (int c = 0; c < 32; ++c) acc[c] = b[col0 + c];

    for (int k = 0; k < DFEAT; k += 4) {
        float4 in4 = *reinterpret_cast<const float4*>(&tile[lane][k]);
#pragma unroll
        for (int c = 0; c < 32; ++c) {
            acc[c] += in4.x * W[(k + 0) * ODIM + col0 + c];
            acc[c] += in4.y * W[(k + 1) * ODIM + col0 + c];
            acc[c] += in4.z * W[(k + 2) * ODIM + col0 + c];
            acc[c] += in4.w * W[(k + 3) * ODIM + col0 + c];
        }
    }
    {
        float nx = tile[lane][128];
        float ny = tile[lane][129];
#pragma unroll
        for (int c = 0; c < 32; ++c) {
            acc[c] += nx * W[128 * ODIM + col0 + c];
            acc[c] += ny * W[129 * ODIM + col0 + c];
        }
    }

    __syncthreads();
#pragma unroll
    for (int c = 0; c < 32; ++c) tile[lane][col0 + c] = fmaxf(acc[c], 0.f);
    __syncthreads();

    for (int i = tid; i < BN * (ODIM / 4); i += 256) {
        int node = i >> 5;
        int k4 = (i & 31) * 4;
        int gn = n0 + node;
        if (gn < NNODES)
            *reinterpret_cast<float4*>(&out[gn * ODIM + k4]) =
                *reinterpret_cast<const float4*>(&tile[node][k4]);
    }
}

extern "C" void kernel_launch(void* const* d_in, const int* in_sizes, int n_in,
                              void* d_out, int out_size, void* d_ws, size_t ws_size,
                              hipStream_t stream) {
    const float* V_node      = (const float*)d_in[0];
    const int*   senders     = (const int*)d_in[1];
    const int*   receivers   = (const int*)d_in[2];
    const float* edge_feats  = (const float*)d_in[3];
    const float* W           = (const float*)d_in[4];
    const float* b           = (const float*)d_in[5];

    // Output layout: V_node_out | I_edge | V_edge
    float*  out_V  = (float*)d_out;
    float*  out_I  = out_V + (size_t)NNODES * ODIM;
    float*  out_Ve = out_I + (size_t)NEDGES * 2;

    // Workspace: net | v2 | [rec] | partials
    float2* net = (float2*)d_ws;
    float2* v2  = net + NNODES;
    ull* rec = (ull*)(v2 + NNODES);

    size_t base_res  = 2 * (size_t)NNODES * sizeof(float2);
    size_t rec_bytes = (size_t)NEDGES * sizeof(ull);            // 51.2 MB
    size_t per_chunk = (size_t)NRANGE * RANGE * sizeof(ull);    // 814 KB
    bool use_rec = ws_size >= base_res + rec_bytes + per_chunk;

    ull* partial;
    int NC;
    if (use_rec) {
        partial = rec + (size_t)NEDGES;
        NC = (int)((ws_size - base_res - rec_bytes) / per_chunk);
    } else {
        partial = rec;
        NC = (ws_size > base_res) ? (int)((ws_size - base_res) / per_chunk) : 1;
    }
    if (NC > NC_MAX) NC = NC_MAX;
    if (NC < 1) NC = 1;

    prep_kernel<<<(NNODES + 255) / 256, 256, 0, stream>>>(V_node, v2);
    stream_kernel<<<(NQUAD + 255) / 256, 256, 0, stream>>>(
        (const int4*)senders, (const int4*)receivers, (const float4*)edge_feats,
        v2, (float4*)out_I, (float4*)out_Ve, use_rec ? rec : nullptr);

    dim3 gridB(NC, NRANGE);
    if (use_rec) {
        int epc = (NEDGES + NC - 1) / NC;
        reduce_rec_kernel<<<gridB, 1024, 0, stream>>>(rec, partial, NC, epc);
    } else {
        int ppc = (NPAIRS + NC - 1) / NC;
        reduce_kernel<<<gridB, 1024, 0, stream>>>(
            (const int2*)senders, (const int2*)receivers, (const float4*)out_I,
            partial, NC, ppc);
    }
    decode_kernel<<<(NNODES + 255) / 256, 256, 0, stream>>>(partial, net, NC);
    mlp_kernel<<<(NNODES + BN - 1) / BN, 256, 0, stream>>>(V_node, net, W, b, out_V);
}